// Round 5
// baseline (1133.757 us; speedup 1.0000x reference)
//
#include <hip/hip_runtime.h>

#define T_LEN 2500
#define B_SZ  128
#define I_SZ  76
#define HID   32
#define G3    96   // 3*HID

// ---------------------------------------------------------------------------
// Kernel 1: xg[dir][b][t][g] = dot(X[b,t,:], W_ih[dir][g,:]) + b_ih[dir][g]
// grid: 1250 blocks x 256 threads, thread = (b,t)   (unchanged from R0)
// ---------------------------------------------------------------------------
__global__ __launch_bounds__(256) void xg_kernel(
    const float* __restrict__ X,
    const float* __restrict__ Wf, const float* __restrict__ bf,
    const float* __restrict__ Wb, const float* __restrict__ bb,
    float* __restrict__ xg)
{
    __shared__ __align__(16) float w[2 * G3 * I_SZ + 2 * G3];
    for (int i = threadIdx.x; i < G3 * I_SZ; i += 256) {
        w[i]               = Wf[i];
        w[G3 * I_SZ + i]   = Wb[i];
    }
    for (int i = threadIdx.x; i < G3; i += 256) {
        w[2 * G3 * I_SZ + i]      = bf[i];
        w[2 * G3 * I_SZ + G3 + i] = bb[i];
    }
    __syncthreads();

    const int tid = blockIdx.x * 256 + threadIdx.x;   // 0..319999
    const int b   = tid / T_LEN;
    const int t   = tid - b * T_LEN;

    float x[I_SZ];
    const float4* xr4 = (const float4*)(X + (size_t)b * T_LEN * I_SZ + (size_t)t * I_SZ);
    #pragma unroll
    for (int i = 0; i < I_SZ / 4; ++i) {
        float4 v = xr4[i];
        x[4*i+0] = v.x; x[4*i+1] = v.y; x[4*i+2] = v.z; x[4*i+3] = v.w;
    }

    #pragma unroll 1
    for (int dir = 0; dir < 2; ++dir) {
        const float4* wd = (const float4*)(w + dir * G3 * I_SZ);
        const float*  bd = w + 2 * G3 * I_SZ + dir * G3;
        float* out = xg + (((size_t)dir * B_SZ + b) * T_LEN + t) * G3;

        #pragma unroll 1
        for (int g0 = 0; g0 < G3; g0 += 4) {
            float a0 = bd[g0+0], a1 = bd[g0+1], a2 = bd[g0+2], a3 = bd[g0+3];
            #pragma unroll
            for (int i4 = 0; i4 < I_SZ / 4; ++i4) {
                float4 w0 = wd[(g0+0) * (I_SZ/4) + i4];
                float4 w1 = wd[(g0+1) * (I_SZ/4) + i4];
                float4 w2 = wd[(g0+2) * (I_SZ/4) + i4];
                float4 w3 = wd[(g0+3) * (I_SZ/4) + i4];
                a0 = fmaf(x[4*i4+0], w0.x, a0); a0 = fmaf(x[4*i4+1], w0.y, a0);
                a0 = fmaf(x[4*i4+2], w0.z, a0); a0 = fmaf(x[4*i4+3], w0.w, a0);
                a1 = fmaf(x[4*i4+0], w1.x, a1); a1 = fmaf(x[4*i4+1], w1.y, a1);
                a1 = fmaf(x[4*i4+2], w1.z, a1); a1 = fmaf(x[4*i4+3], w1.w, a1);
                a2 = fmaf(x[4*i4+0], w2.x, a2); a2 = fmaf(x[4*i4+1], w2.y, a2);
                a2 = fmaf(x[4*i4+2], w2.z, a2); a2 = fmaf(x[4*i4+3], w2.w, a2);
                a3 = fmaf(x[4*i4+0], w3.x, a3); a3 = fmaf(x[4*i4+1], w3.y, a3);
                a3 = fmaf(x[4*i4+2], w3.z, a3); a3 = fmaf(x[4*i4+3], w3.w, a3);
            }
            float4 o; o.x = a0; o.y = a1; o.z = a2; o.w = a3;
            *(float4*)(out + g0) = o;
        }
    }
}

// ---------------------------------------------------------------------------
// Kernel 2: sequential GRU scan. One wave per (b,dir) pair.
// R4: h state in 32 wave-uniform SGPRs via v_readlane (no LDS h round-trip),
//     full-32 dots, branchless clamped prefetch (PFD=4, 2500%4==0 -> all
//     ring indices static), z transfer via __shfl_xor (known-good codegen)
//     with a [0,1] clamp making the recurrence provably bounded (no NaN).
// lane k (lo): owns r_k and n_k; lane 32+k (hi): owns z_k (n-dot duplicated).
// grid: 256 blocks x 64 threads
// ---------------------------------------------------------------------------
#define PFD 4   // prefetch ring depth (power of 2, divides T_LEN, matches unroll)

__global__ __launch_bounds__(64) void scan_kernel(
    const float* __restrict__ xg,
    const float* __restrict__ Whf, const float* __restrict__ bhf,
    const float* __restrict__ Whb, const float* __restrict__ bhb,
    float* __restrict__ out)
{
    const int l  = threadIdx.x;
    const int k  = l & 31;
    const int lo = (l < 32);
    const int p  = blockIdx.x;       // pair index 0..255
    const int dir = p >> 7;
    const int b   = p & 127;

    const float* Wh = dir ? Whb : Whf;
    const float* bh = dir ? bhb : bhf;

    // w1: lo lanes -> W_r row k, hi lanes -> W_z row k. w2: W_n row k (both).
    float w1[HID], w2[HID];
    {
        const float4* q1 = (const float4*)(Wh + ((lo ? 0 : HID) + k) * HID);
        const float4* q2 = (const float4*)(Wh + (2 * HID + k) * HID);
        #pragma unroll
        for (int i = 0; i < HID / 4; ++i) {
            float4 v = q1[i];
            w1[4*i+0]=v.x; w1[4*i+1]=v.y; w1[4*i+2]=v.z; w1[4*i+3]=v.w;
            float4 u = q2[i];
            w2[4*i+0]=u.x; w2[4*i+1]=u.y; w2[4*i+2]=u.z; w2[4*i+3]=u.w;
        }
    }
    const float b1 = bh[(lo ? 0 : HID) + k];   // b_r or b_z
    const float b2 = bh[2 * HID + k];          // b_n

    // xg stream for this pair; backward walks t downward
    const float* xbase = xg + ((size_t)p * T_LEN + (dir ? (T_LEN - 1) : 0)) * G3;
    const int step = dir ? -G3 : G3;

    // h state: wave-uniform SGPRs
    float hs[HID];
    #pragma unroll
    for (int j = 0; j < HID; ++j) hs[j] = 0.f;
    float hk = 0.f;   // lane-private h_k (authoritative in lo lanes)

    // prefetch ring: p1 = xg[t][l] (xr lo / xz hi), p2 = xg[t][64+k] (xn)
    float p1[PFD], p2[PFD];
    #pragma unroll
    for (int d = 0; d < PFD; ++d) {
        const float* q = xbase + (long)d * step;
        p1[d] = q[l];
        p2[d] = q[64 + k];
    }

    #pragma unroll PFD
    for (int t = 0; t < T_LEN; ++t) {
        const int slot = t & (PFD - 1);
        const float x1 = p1[slot];     // lo: xr, hi: xz
        const float xn = p2[slot];

        // branchless clamped prefetch: no control flow -> precise vmcnt
        {
            const int tp = (t + PFD < T_LEN) ? (t + PFD) : (T_LEN - 1);
            const float* q = xbase + (long)tp * step;
            p1[slot] = q[l];
            p2[slot] = q[64 + k];
        }

        // off-chain precomputes (x available PFD steps early)
        const float pre1 = -1.442695040888963f * x1;
        const float qx   =  2.885390081777927f * xn;

        // full 32-length dots: VGPR weight x uniform SGPR h, 2 indep chains
        float d1 = b1, d2 = b2;
        #pragma unroll
        for (int j = 0; j < HID; ++j) {
            d1 = fmaf(w1[j], hs[j], d1);
            d2 = fmaf(w2[j], hs[j], d2);
        }

        // shared sigmoid: lo -> r, hi -> z   (arg = -1.4427*(x1+d1))
        const float s1 = __builtin_amdgcn_rcpf(
            1.f + __builtin_amdgcn_exp2f(fmaf(-1.442695040888963f, d1, pre1)));

        // bring z (hi half) down to lo lanes; clamp to [0,1] (no-op for a
        // correct sigmoid) -> recurrence provably bounded, NaN impossible
        float zk = __shfl_xor(s1, 32, 64);
        zk = fminf(1.f, fmaxf(0.f, zk));

        // n = tanh(xn + r*d2) = 1 - 2*rcp(exp2(2.885*(xn + r*d2)) + 1)
        // (exact limits at +-inf -> no clamp needed)
        const float q2v = 2.885390081777927f * d2;   // off-chain vs sigmoid
        const float E1  = __builtin_amdgcn_exp2f(fmaf(s1, q2v, qx));
        const float n   = fmaf(-2.f, __builtin_amdgcn_rcpf(E1 + 1.f), 1.f);

        // h_new = n + z*(h - n)   (hi lanes: zk = r-clamped, hk garbage-but-
        // bounded; only lanes 0..31 are read back below)
        hk = fmaf(zk, hk - n, n);

        // broadcast h_new to wave-uniform SGPRs (lanes 0..31 authoritative)
        #pragma unroll
        for (int j = 0; j < HID; ++j)
            hs[j] = __builtin_bit_cast(float,
                        __builtin_amdgcn_readlane(__builtin_bit_cast(int, hk), j));
    }

    // output: (B, 2, H)
    if (lo) out[(b * 2 + dir) * HID + k] = hk;
}

extern "C" void kernel_launch(void* const* d_in, const int* in_sizes, int n_in,
                              void* d_out, int out_size, void* d_ws, size_t ws_size,
                              hipStream_t stream) {
    const float* X    = (const float*)d_in[0];
    const float* Wihf = (const float*)d_in[1];
    const float* Whhf = (const float*)d_in[2];
    const float* bihf = (const float*)d_in[3];
    const float* bhhf = (const float*)d_in[4];
    const float* Wihb = (const float*)d_in[5];
    const float* Whhb = (const float*)d_in[6];
    const float* bihb = (const float*)d_in[7];
    const float* bhhb = (const float*)d_in[8];
    float* out = (float*)d_out;
    float* xg  = (float*)d_ws;

    const size_t needed = (size_t)2 * B_SZ * T_LEN * G3 * sizeof(float); // 245.76 MB
    if (ws_size < needed) return;

    xg_kernel<<<(B_SZ * T_LEN) / 256, 256, 0, stream>>>(X, Wihf, bihf, Wihb, bihb, xg);
    scan_kernel<<<256, 64, 0, stream>>>(xg, Whhf, bhhf, Whhb, bhhb, out);
}